// Round 3
// baseline (273.188 us; speedup 1.0000x reference)
//
#include <hip/hip_runtime.h>
#include <hip/hip_bf16.h>

// Shapes (fixed by the problem)
#define BATCH  4
#define TSEQ   2048
#define CDIM   1024
#define NHEAD  16
#define DHEAD  64
#define MROWS  (BATCH * TSEQ)      // 8192
#define QKVCOL (3 * CDIM)          // 3072

typedef __bf16 bf16x8 __attribute__((ext_vector_type(8)));
typedef float  f32x4  __attribute__((ext_vector_type(4)));

// hardware exp2 (v_exp_f32). __exp2f collides with a glibc macro (R12).
#define EXP2F(x) __builtin_amdgcn_exp2f(x)

__device__ __forceinline__ unsigned short f2bf(float f) {
  union { float f; unsigned int i; } v; v.f = f;
  unsigned int i = v.i;
  return (unsigned short)((i + 0x7fffu + ((i >> 16) & 1u)) >> 16);  // RNE
}

__device__ __forceinline__ void load16_to_lds(const void* g, void* l) {
  __builtin_amdgcn_global_load_lds(
      (const __attribute__((address_space(1))) unsigned int*)g,
      (__attribute__((address_space(3))) unsigned int*)l, 16, 0, 0);
}

// ---------------------------------------------------------------------------
// Elementwise cast fp32 -> bf16
// ---------------------------------------------------------------------------
__global__ __launch_bounds__(256) void cast_f32_bf16(
    const float* __restrict__ in, unsigned short* __restrict__ out, int n) {
  const int i = (blockIdx.x * 256 + threadIdx.x) * 8;
  if (i >= n) return;
  float4 a = *(const float4*)(in + i);
  float4 b = *(const float4*)(in + i + 4);
  unsigned short v[8] = {f2bf(a.x), f2bf(a.y), f2bf(a.z), f2bf(a.w),
                         f2bf(b.x), f2bf(b.y), f2bf(b.z), f2bf(b.w)};
  *(uint4*)(out + i) = *(const uint4*)v;
}

// ---------------------------------------------------------------------------
// Fused transpose + cast: fp32 [R,C] -> bf16 [C,R]
// ---------------------------------------------------------------------------
__global__ __launch_bounds__(256) void transpose_cast(
    const float* __restrict__ in, unsigned short* __restrict__ out,
    int R, int C) {
  __shared__ float tile[64][68];
  const int t  = threadIdx.x;
  const int r0 = blockIdx.y * 64;
  const int c0 = blockIdx.x * 64;
  const int tr = t >> 2;
  const int tc = (t & 3) * 16;

  const float4* src = (const float4*)(in + (size_t)(r0 + tr) * C + c0 + tc);
#pragma unroll
  for (int i = 0; i < 4; i++)
    *(float4*)&tile[tr][tc + 4 * i] = src[i];
  __syncthreads();

  unsigned short vals[16];
#pragma unroll
  for (int k = 0; k < 16; k++) vals[k] = f2bf(tile[tc + k][tr]);
  uint4* dst = (uint4*)(out + (size_t)(c0 + tr) * R + r0 + tc);
  dst[0] = ((const uint4*)vals)[0];
  dst[1] = ((const uint4*)vals)[1];
}

// ---------------------------------------------------------------------------
// Transpose bf16 V: Vb [B*T,1024]=[b t][h d] -> vt [b h][d=64][T=2048]
// ---------------------------------------------------------------------------
__global__ __launch_bounds__(256) void transpose_v(
    const unsigned short* __restrict__ Vb, unsigned short* __restrict__ vt) {
  __shared__ unsigned short tile[64][72];
  const int t  = threadIdx.x;
  const int kt = blockIdx.x;
  const int bh = blockIdx.y;
  const int b  = bh >> 4, h = bh & 15;
  const int tr = t >> 2;
  const int tc = (t & 3) * 16;

  const unsigned short* src = Vb + (size_t)(b * TSEQ + kt * 64 + tr) * CDIM + h * 64 + tc;
  *(uint4*)&tile[tr][tc + 0] = ((const uint4*)src)[0];
  *(uint4*)&tile[tr][tc + 8] = ((const uint4*)src)[1];
  __syncthreads();

  unsigned short vals[16];
#pragma unroll
  for (int k = 0; k < 16; k++) vals[k] = tile[tc + k][tr];
  unsigned short* dst = vt + ((size_t)bh * 64 + tr) * TSEQ + kt * 64 + tc;
  ((uint4*)dst)[0] = ((const uint4*)vals)[0];
  ((uint4*)dst)[1] = ((const uint4*)vals)[1];
}

// ---------------------------------------------------------------------------
// QKV GEMM (m97-style DMA staging). Q scaled by 0.125*log2(e) for exp2 path.
// ---------------------------------------------------------------------------
__global__ __launch_bounds__(256) void gemm_qkv(
    const unsigned short* __restrict__ A, const unsigned short* __restrict__ Bt,
    unsigned short* __restrict__ Qb, unsigned short* __restrict__ Kb,
    unsigned short* __restrict__ Vb) {
  __shared__ unsigned short ldsA[128 * 32];
  __shared__ unsigned short ldsB[128 * 32];

  const int tid  = threadIdx.x;
  const int lane = tid & 63;
  const int wave = tid >> 6;
  const int m0   = blockIdx.y * 128;
  const int n0   = blockIdx.x * 128;
  const int wr   = wave >> 1;
  const int wc   = wave & 1;
  const int quad = lane >> 4;
  const int l16  = lane & 15;

  f32x4 acc[4][4] = {};
  const int rsub = lane >> 2;
  const int csub = (lane & 3) * 8;

  for (int k0 = 0; k0 < CDIM; k0 += 32) {
    __syncthreads();
#pragma unroll
    for (int i = 0; i < 2; i++) {
      const int rowbase = i * 64 + wave * 16;
      load16_to_lds(A  + (size_t)(m0 + rowbase + rsub) * CDIM + k0 + csub, &ldsA[rowbase * 32]);
      load16_to_lds(Bt + (size_t)(n0 + rowbase + rsub) * CDIM + k0 + csub, &ldsB[rowbase * 32]);
    }
    __syncthreads();

    bf16x8 fa[4], fb[4];
#pragma unroll
    for (int i = 0; i < 4; i++)
      fa[i] = *(const bf16x8*)&ldsA[(wr * 64 + i * 16 + l16) * 32 + quad * 8];
#pragma unroll
    for (int j = 0; j < 4; j++)
      fb[j] = *(const bf16x8*)&ldsB[(wc * 64 + j * 16 + l16) * 32 + quad * 8];

#pragma unroll
    for (int i = 0; i < 4; i++)
#pragma unroll
      for (int j = 0; j < 4; j++)
        acc[i][j] = __builtin_amdgcn_mfma_f32_16x16x32_bf16(fa[i], fb[j], acc[i][j], 0, 0, 0);
  }

  const int seg = n0 >> 10;                       // 0=Q 1=K 2=V
  unsigned short* dst = seg == 0 ? Qb : (seg == 1 ? Kb : Vb);
  const float scl = seg == 0 ? 0.18033688f : 1.0f;  // 0.125*log2(e)
#pragma unroll
  for (int i = 0; i < 4; i++) {
    const int row = m0 + wr * 64 + i * 16 + quad * 4;
#pragma unroll
    for (int j = 0; j < 4; j++) {
      const int col = ((n0 & 1023) + wc * 64 + j * 16 + l16);
#pragma unroll
      for (int r = 0; r < 4; r++)
        dst[(size_t)(row + r) * CDIM + col] = f2bf(acc[i][j][r] * scl);
    }
  }
}

// ---------------------------------------------------------------------------
// Out-projection GEMM (DMA staging).
// ---------------------------------------------------------------------------
__global__ __launch_bounds__(256) void gemm_out(
    const unsigned short* __restrict__ A, const unsigned short* __restrict__ Bt,
    float* __restrict__ Cmat, const float* __restrict__ bias) {
  __shared__ unsigned short ldsA[128 * 32];
  __shared__ unsigned short ldsB[128 * 32];

  const int tid  = threadIdx.x;
  const int lane = tid & 63;
  const int wave = tid >> 6;
  const int m0   = blockIdx.y * 128;
  const int n0   = blockIdx.x * 128;
  const int wr   = wave >> 1;
  const int wc   = wave & 1;
  const int quad = lane >> 4;
  const int l16  = lane & 15;

  f32x4 acc[4][4] = {};
  const int rsub = lane >> 2;
  const int csub = (lane & 3) * 8;

  for (int k0 = 0; k0 < CDIM; k0 += 32) {
    __syncthreads();
#pragma unroll
    for (int i = 0; i < 2; i++) {
      const int rowbase = i * 64 + wave * 16;
      load16_to_lds(A  + (size_t)(m0 + rowbase + rsub) * CDIM + k0 + csub, &ldsA[rowbase * 32]);
      load16_to_lds(Bt + (size_t)(n0 + rowbase + rsub) * CDIM + k0 + csub, &ldsB[rowbase * 32]);
    }
    __syncthreads();

    bf16x8 fa[4], fb[4];
#pragma unroll
    for (int i = 0; i < 4; i++)
      fa[i] = *(const bf16x8*)&ldsA[(wr * 64 + i * 16 + l16) * 32 + quad * 8];
#pragma unroll
    for (int j = 0; j < 4; j++)
      fb[j] = *(const bf16x8*)&ldsB[(wc * 64 + j * 16 + l16) * 32 + quad * 8];

#pragma unroll
    for (int i = 0; i < 4; i++)
#pragma unroll
      for (int j = 0; j < 4; j++)
        acc[i][j] = __builtin_amdgcn_mfma_f32_16x16x32_bf16(fa[i], fb[j], acc[i][j], 0, 0, 0);
  }

#pragma unroll
  for (int i = 0; i < 4; i++) {
    const int row = m0 + wr * 64 + i * 16 + quad * 4;
#pragma unroll
    for (int j = 0; j < 4; j++) {
      const int col = n0 + wc * 64 + j * 16 + l16;
      const float bv2 = bias[col];
#pragma unroll
      for (int r = 0; r < 4; r++)
        Cmat[(size_t)(row + r) * CDIM + col] = acc[i][j][r] + bv2;
    }
  }
}

// ---------------------------------------------------------------------------
// MFMA causal flash attention, v8 — 8 waves x 1 q-group (was 4 waves x 2).
// R2 diagnosis: MfmaUtil 20 / VALUBusy 39 / HBM 7 / conflicts 0 / occupancy
// 18.5% => latency-bound serial S->P->O chain with only 2 waves/SIMD. Split
// the A/B groups across waves: 512-thread blocks, wave w<4 handles j=4p+w,
// w>=4 handles j=67-4p-w. Same grid (512), same LDS (64KB: K/V dbuf 32KB +
// P 8x4KB), 2 blocks/CU -> 16 waves/CU (was 8), 4 waves/SIMD. Per-wave
// state halves (one aq/O/l/S set) -> fits 128 VGPR under lb(512,4).
// CU load balance: blocks pair (id, id+256) on a CU; old p-pairs (p,p+4)
// gave per-CU KT sums 56/52/48/44 (27% spread). Remap id>=256: p=11-pr ->
// pairs (0,7),(1,6),(2,5),(3,4) = sums 50/50/52/50. ~7% makespan win.
// Swizzle (v7, verified): read base rb_ks*, P-write pwoff[r][nt], staging
// st = srow*64 + (scol ^ ((srow&7)<<3)) — all kt-invariant, zero inner VALU.
// One barrier per kt (store buf[kt&1] -> barrier -> compute buf[kt&1]).
// ---------------------------------------------------------------------------
__global__ __launch_bounds__(512, 4) void flash_attn_mfma(
    const unsigned short* __restrict__ Qb, const unsigned short* __restrict__ Kb,
    const unsigned short* __restrict__ vt, unsigned short* __restrict__ aout) {
  __shared__ unsigned short K_lds[2 * 64 * 64];     // double-buffered
  __shared__ unsigned short V_lds[2 * 64 * 64];     // double-buffered
  __shared__ unsigned short P_lds[8][32 * 64];      // per-wave private

  const int tid  = threadIdx.x;
  const int lane = tid & 63;
  const int wave = tid >> 6;          // 0..7
  const int id   = blockIdx.x;
  const int bh   = id & 63;           // XCD bucket
  const int pr   = id >> 6;           // 0..7 raw
  const int p    = pr < 4 ? pr : 11 - pr;   // balance remap: pairs sum ~50
  const int b    = bh >> 4, h = bh & 15;
  const int quad = lane >> 4;
  const int l16  = lane & 15;

  const int jw   = (wave < 4) ? (p * 4 + wave) : (67 - 4 * p - wave);  // 0..63
  const int wq   = jw * 32;
  const int endW = (jw >> 1) + 1;             // active tiles for this wave
  const int KT   = ((63 - 4 * p) >> 1) + 1;   // block-uniform iterations

  // ---- hoisted swizzle bases (kt-invariant) ----
  // read side: phys(row=X*16+l16, col=ks*32+quad*8) = X*1024 + rb_ks
  const int cx34   = (quad * 8) ^ ((l16 & 3) << 3);          // bits 3-4
  const int rb_ks0 = l16 * 64 + ((l16 & 4) << 3) + cx34;     // ks=0
  const int rb_ks1 = l16 * 64 + (32 ^ ((l16 & 4) << 3)) + cx34;  // ks=1
  // P write side: phys(prow=mt*16+quad*4+r, pcol=nt*16+l16) = mt*1024 + pwoff[r][nt]
  int pwoff[4][4];
#pragma unroll
  for (int r = 0; r < 4; r++)
#pragma unroll
    for (int nt = 0; nt < 4; nt++)
      pwoff[r][nt] = (quad * 4 + r) * 64
                   + ((nt * 16) ^ (((quad & 1) << 5) | ((r & 2) << 3)))
                   + (l16 ^ ((r & 1) << 3));
  // staging write side (512 threads, one uint4 = 16B each for K and V)
  const int srow = tid >> 3;          // 0..63
  const int scol = (tid & 7) * 8;     // 0,8,...,56
  const int st   = srow * 64 + (scol ^ ((srow & 7) << 3));

  // Q A-frags for this wave's q-tile (Q pre-scaled by 0.125*log2e)
  bf16x8 aq[2][2];
#pragma unroll
  for (int mt = 0; mt < 2; mt++)
#pragma unroll
    for (int ks = 0; ks < 2; ks++)
      aq[mt][ks] = *(const bf16x8*)(Qb + (size_t)(b * TSEQ + wq + mt * 16 + l16) * CDIM
                                       + h * 64 + ks * 32 + quad * 8);

  f32x4 O[2][4] = {};
  f32x4 l[2] = {};

  bf16x8 ones;
#pragma unroll
  for (int jj = 0; jj < 8; jj++) ones[jj] = (__bf16)1.0f;

  const unsigned short* Kg = Kb + (size_t)b * TSEQ * CDIM + h * 64;
  const unsigned short* Vg = vt + (size_t)bh * 64 * TSEQ;
  unsigned short* pw = &P_lds[wave][0];

  // preload tile 0 into staging registers
  uint4 kr = *(const uint4*)(Kg + (size_t)srow * CDIM + scol);
  uint4 vr = *(const uint4*)(Vg + (size_t)srow * TSEQ + scol);

  for (int kt = 0; kt < KT; kt++) {
    const int kbase = kt * 64;
    const int bo    = (kt & 1) << 12;    // double-buffer offset (u16 units)

    *(uint4*)&K_lds[bo + st] = kr;
    *(uint4*)&V_lds[bo + st] = vr;
    __syncthreads();   // staged tile visible; ONE barrier per iteration

    // prefetch next tile: lands during ~2000 cyc of compute
    if (kt + 1 < KT) {
      kr = *(const uint4*)(Kg + (size_t)(kbase + 64 + srow) * CDIM + scol);
      vr = *(const uint4*)(Vg + (size_t)srow * TSEQ + kbase + 64 + scol);
    }

    if (kt < endW) {
      // ---- S phase ----
      f32x4 S[2][4] = {};
#pragma unroll
      for (int nt = 0; nt < 4; nt++)
#pragma unroll
        for (int ks = 0; ks < 2; ks++) {
          bf16x8 bk = *(const bf16x8*)&K_lds[bo + nt * 1024 + (ks ? rb_ks1 : rb_ks0)];
          S[0][nt] = __builtin_amdgcn_mfma_f32_16x16x32_bf16(aq[0][ks], bk, S[0][nt], 0, 0, 0);
          S[1][nt] = __builtin_amdgcn_mfma_f32_16x16x32_bf16(aq[1][ks], bk, S[1][nt], 0, 0, 0);
        }

      // ---- P phase (exp2; mask only on diagonal tiles) ----
      const bool masked = (kbase + 64 > wq);
#pragma unroll
      for (int mt = 0; mt < 2; mt++) {
#pragma unroll
        for (int nt = 0; nt < 4; nt++)
#pragma unroll
          for (int r = 0; r < 4; r += 2) {
            float s0 = S[mt][nt][r], s1 = S[mt][nt][r + 1];
            if (masked) {
              const int qrow = wq + mt * 16 + quad * 4 + r;
              const int key  = kbase + nt * 16 + l16;
              s0 = (key <= qrow)     ? s0 : -1e30f;
              s1 = (key <= qrow + 1) ? s1 : -1e30f;
            }
            __hip_bfloat162 p2 = __float22bfloat162_rn(make_float2(EXP2F(s0), EXP2F(s1)));
            unsigned int u; __builtin_memcpy(&u, &p2, 4);
            pw[pwoff[r    ][nt] + mt * 1024] = (unsigned short)u;
            pw[pwoff[r + 1][nt] + mt * 1024] = (unsigned short)(u >> 16);
          }
      }

      // ---- O phase ----
#pragma unroll
      for (int ks = 0; ks < 2; ks++) {
        const int rb = ks ? rb_ks1 : rb_ks0;
        bf16x8 bv[4];
#pragma unroll
        for (int nt = 0; nt < 4; nt++)
          bv[nt] = *(const bf16x8*)&V_lds[bo + nt * 1024 + rb];
#pragma unroll
        for (int mt = 0; mt < 2; mt++) {
          bf16x8 ap = *(const bf16x8*)&pw[mt * 1024 + rb];
          l[mt] = __builtin_amdgcn_mfma_f32_16x16x32_bf16(ap, ones, l[mt], 0, 0, 0);
#pragma unroll
          for (int nt = 0; nt < 4; nt++)
            O[mt][nt] = __builtin_amdgcn_mfma_f32_16x16x32_bf16(ap, bv[nt], O[mt][nt], 0, 0, 0);
        }
      }
    }
  }

  // epilogue: O / l -> aout [b t][h d]
#pragma unroll
  for (int mt = 0; mt < 2; mt++) {
    float inv[4];
#pragma unroll
    for (int r = 0; r < 4; r++) inv[r] = 1.0f / l[mt][r];
    unsigned short* oa = aout + (size_t)(b * TSEQ + wq + mt * 16 + quad * 4) * CDIM + h * 64 + l16;
#pragma unroll
    for (int nt = 0; nt < 4; nt++)
#pragma unroll
      for (int r = 0; r < 4; r++)
        oa[(size_t)r * CDIM + nt * 16] = f2bf(O[mt][nt][r] * inv[r]);
  }
}

// ---------------------------------------------------------------------------
extern "C" void kernel_launch(void* const* d_in, const int* in_sizes, int n_in,
                              void* d_out, int out_size, void* d_ws, size_t ws_size,
                              hipStream_t stream) {
  (void)in_sizes; (void)n_in; (void)out_size;
  const float* x     = (const float*)d_in[0];  // [8192,1024] fp32
  const float* w_qkv = (const float*)d_in[1];  // [1024,3072] fp32
  const float* w_out = (const float*)d_in[2];  // [1024,1024] fp32
  const float* b_out = (const float*)d_in[3];  // [1024] fp32
  float* out = (float*)d_out;                  // [8192,1024] fp32

  // Workspace: exactly 72 MiB (proven footprint).
  const size_t WS_NEED = 75497472;
  if (ws_size < WS_NEED) return;

  char* ws = (char*)d_ws;
  unsigned short* Qb    = (unsigned short*)(ws);
  unsigned short* Kb    = (unsigned short*)(ws + 16777216);
  unsigned short* Vb    = (unsigned short*)(ws + 33554432);
  unsigned short* aout  = (unsigned short*)(ws + 33554432);  // alias of Vb
  unsigned short* vt    = (unsigned short*)(ws + 50331648);
  unsigned short* xb    = (unsigned short*)(ws + 50331648);  // alias of vt
  unsigned short* wqkvT = (unsigned short*)(ws + 67108864);
  unsigned short* woutT = (unsigned short*)(ws + 73400320);

  // 1) x -> bf16 (xb, dead after gemm_qkv); weights -> B^T bf16
  cast_f32_bf16<<<MROWS * CDIM / 2048, 256, 0, stream>>>(x, xb, MROWS * CDIM);
  transpose_cast<<<dim3(QKVCOL / 64, CDIM / 64), 256, 0, stream>>>(w_qkv, wqkvT, CDIM, QKVCOL);
  transpose_cast<<<dim3(CDIM / 64, CDIM / 64), 256, 0, stream>>>(w_out, woutT, CDIM, CDIM);

  // 2) QKV projection (Q pre-scaled 0.125*log2e)
  gemm_qkv<<<dim3(QKVCOL / 128, MROWS / 128), 256, 0, stream>>>(xb, wqkvT, Qb, Kb, Vb);

  // 3) V -> V^T per (b,h)   (vt overwrites xb — xb dead)
  transpose_v<<<dim3(TSEQ / 64, BATCH * NHEAD), 256, 0, stream>>>(Vb, vt);

  // 4) balanced 8-wave MFMA flash attention -> aout (overwrites Vb)
  flash_attn_mfma<<<dim3(8 * 64), 512, 0, stream>>>(Qb, Kb, vt, aout);

  // 5) out-projection + bias
  gemm_out<<<dim3(CDIM / 128, MROWS / 128), 256, 0, stream>>>(aout, woutT, out, b_out);
}

// Round 7
// 266.638 us; speedup vs baseline: 1.0246x; 1.0246x over previous
//
#include <hip/hip_runtime.h>
#include <hip/hip_bf16.h>

// Shapes (fixed by the problem)
#define BATCH  4
#define TSEQ   2048
#define CDIM   1024
#define NHEAD  16
#define DHEAD  64
#define MROWS  (BATCH * TSEQ)      // 8192
#define QKVCOL (3 * CDIM)          // 3072

typedef __bf16 bf16x8 __attribute__((ext_vector_type(8)));
typedef float  f32x4  __attribute__((ext_vector_type(4)));

// hardware exp2 (v_exp_f32). __exp2f collides with a glibc macro (R12).
#define EXP2F(x) __builtin_amdgcn_exp2f(x)

__device__ __forceinline__ unsigned short f2bf(float f) {
  union { float f; unsigned int i; } v; v.f = f;
  unsigned int i = v.i;
  return (unsigned short)((i + 0x7fffu + ((i >> 16) & 1u)) >> 16);  // RNE
}

__device__ __forceinline__ void load16_to_lds(const void* g, void* l) {
  __builtin_amdgcn_global_load_lds(
      (const __attribute__((address_space(1))) unsigned int*)g,
      (__attribute__((address_space(3))) unsigned int*)l, 16, 0, 0);
}

// ---------------------------------------------------------------------------
// Elementwise cast fp32 -> bf16
// ---------------------------------------------------------------------------
__global__ __launch_bounds__(256) void cast_f32_bf16(
    const float* __restrict__ in, unsigned short* __restrict__ out, int n) {
  const int i = (blockIdx.x * 256 + threadIdx.x) * 8;
  if (i >= n) return;
  float4 a = *(const float4*)(in + i);
  float4 b = *(const float4*)(in + i + 4);
  unsigned short v[8] = {f2bf(a.x), f2bf(a.y), f2bf(a.z), f2bf(a.w),
                         f2bf(b.x), f2bf(b.y), f2bf(b.z), f2bf(b.w)};
  *(uint4*)(out + i) = *(const uint4*)v;
}

// ---------------------------------------------------------------------------
// Fused transpose + cast: fp32 [R,C] -> bf16 [C,R]
// ---------------------------------------------------------------------------
__global__ __launch_bounds__(256) void transpose_cast(
    const float* __restrict__ in, unsigned short* __restrict__ out,
    int R, int C) {
  __shared__ float tile[64][68];
  const int t  = threadIdx.x;
  const int r0 = blockIdx.y * 64;
  const int c0 = blockIdx.x * 64;
  const int tr = t >> 2;
  const int tc = (t & 3) * 16;

  const float4* src = (const float4*)(in + (size_t)(r0 + tr) * C + c0 + tc);
#pragma unroll
  for (int i = 0; i < 4; i++)
    *(float4*)&tile[tr][tc + 4 * i] = src[i];
  __syncthreads();

  unsigned short vals[16];
#pragma unroll
  for (int k = 0; k < 16; k++) vals[k] = f2bf(tile[tc + k][tr]);
  uint4* dst = (uint4*)(out + (size_t)(c0 + tr) * R + r0 + tc);
  dst[0] = ((const uint4*)vals)[0];
  dst[1] = ((const uint4*)vals)[1];
}

// ---------------------------------------------------------------------------
// Transpose bf16 V: Vb [B*T,1024]=[b t][h d] -> vt [b h][d=64][T=2048]
// ---------------------------------------------------------------------------
__global__ __launch_bounds__(256) void transpose_v(
    const unsigned short* __restrict__ Vb, unsigned short* __restrict__ vt) {
  __shared__ unsigned short tile[64][72];
  const int t  = threadIdx.x;
  const int kt = blockIdx.x;
  const int bh = blockIdx.y;
  const int b  = bh >> 4, h = bh & 15;
  const int tr = t >> 2;
  const int tc = (t & 3) * 16;

  const unsigned short* src = Vb + (size_t)(b * TSEQ + kt * 64 + tr) * CDIM + h * 64 + tc;
  *(uint4*)&tile[tr][tc + 0] = ((const uint4*)src)[0];
  *(uint4*)&tile[tr][tc + 8] = ((const uint4*)src)[1];
  __syncthreads();

  unsigned short vals[16];
#pragma unroll
  for (int k = 0; k < 16; k++) vals[k] = tile[tc + k][tr];
  unsigned short* dst = vt + ((size_t)bh * 64 + tr) * TSEQ + kt * 64 + tc;
  ((uint4*)dst)[0] = ((const uint4*)vals)[0];
  ((uint4*)dst)[1] = ((const uint4*)vals)[1];
}

// ---------------------------------------------------------------------------
// QKV GEMM (m97-style DMA staging). Q scaled by 0.125*log2(e) for exp2 path.
// ---------------------------------------------------------------------------
__global__ __launch_bounds__(256) void gemm_qkv(
    const unsigned short* __restrict__ A, const unsigned short* __restrict__ Bt,
    unsigned short* __restrict__ Qb, unsigned short* __restrict__ Kb,
    unsigned short* __restrict__ Vb) {
  __shared__ unsigned short ldsA[128 * 32];
  __shared__ unsigned short ldsB[128 * 32];

  const int tid  = threadIdx.x;
  const int lane = tid & 63;
  const int wave = tid >> 6;
  const int m0   = blockIdx.y * 128;
  const int n0   = blockIdx.x * 128;
  const int wr   = wave >> 1;
  const int wc   = wave & 1;
  const int quad = lane >> 4;
  const int l16  = lane & 15;

  f32x4 acc[4][4] = {};
  const int rsub = lane >> 2;
  const int csub = (lane & 3) * 8;

  for (int k0 = 0; k0 < CDIM; k0 += 32) {
    __syncthreads();
#pragma unroll
    for (int i = 0; i < 2; i++) {
      const int rowbase = i * 64 + wave * 16;
      load16_to_lds(A  + (size_t)(m0 + rowbase + rsub) * CDIM + k0 + csub, &ldsA[rowbase * 32]);
      load16_to_lds(Bt + (size_t)(n0 + rowbase + rsub) * CDIM + k0 + csub, &ldsB[rowbase * 32]);
    }
    __syncthreads();

    bf16x8 fa[4], fb[4];
#pragma unroll
    for (int i = 0; i < 4; i++)
      fa[i] = *(const bf16x8*)&ldsA[(wr * 64 + i * 16 + l16) * 32 + quad * 8];
#pragma unroll
    for (int j = 0; j < 4; j++)
      fb[j] = *(const bf16x8*)&ldsB[(wc * 64 + j * 16 + l16) * 32 + quad * 8];

#pragma unroll
    for (int i = 0; i < 4; i++)
#pragma unroll
      for (int j = 0; j < 4; j++)
        acc[i][j] = __builtin_amdgcn_mfma_f32_16x16x32_bf16(fa[i], fb[j], acc[i][j], 0, 0, 0);
  }

  const int seg = n0 >> 10;                       // 0=Q 1=K 2=V
  unsigned short* dst = seg == 0 ? Qb : (seg == 1 ? Kb : Vb);
  const float scl = seg == 0 ? 0.18033688f : 1.0f;  // 0.125*log2(e)
#pragma unroll
  for (int i = 0; i < 4; i++) {
    const int row = m0 + wr * 64 + i * 16 + quad * 4;
#pragma unroll
    for (int j = 0; j < 4; j++) {
      const int col = ((n0 & 1023) + wc * 64 + j * 16 + l16);
#pragma unroll
      for (int r = 0; r < 4; r++)
        dst[(size_t)(row + r) * CDIM + col] = f2bf(acc[i][j][r] * scl);
    }
  }
}

// ---------------------------------------------------------------------------
// Out-projection GEMM (DMA staging).
// ---------------------------------------------------------------------------
__global__ __launch_bounds__(256) void gemm_out(
    const unsigned short* __restrict__ A, const unsigned short* __restrict__ Bt,
    float* __restrict__ Cmat, const float* __restrict__ bias) {
  __shared__ unsigned short ldsA[128 * 32];
  __shared__ unsigned short ldsB[128 * 32];

  const int tid  = threadIdx.x;
  const int lane = tid & 63;
  const int wave = tid >> 6;
  const int m0   = blockIdx.y * 128;
  const int n0   = blockIdx.x * 128;
  const int wr   = wave >> 1;
  const int wc   = wave & 1;
  const int quad = lane >> 4;
  const int l16  = lane & 15;

  f32x4 acc[4][4] = {};
  const int rsub = lane >> 2;
  const int csub = (lane & 3) * 8;

  for (int k0 = 0; k0 < CDIM; k0 += 32) {
    __syncthreads();
#pragma unroll
    for (int i = 0; i < 2; i++) {
      const int rowbase = i * 64 + wave * 16;
      load16_to_lds(A  + (size_t)(m0 + rowbase + rsub) * CDIM + k0 + csub, &ldsA[rowbase * 32]);
      load16_to_lds(Bt + (size_t)(n0 + rowbase + rsub) * CDIM + k0 + csub, &ldsB[rowbase * 32]);
    }
    __syncthreads();

    bf16x8 fa[4], fb[4];
#pragma unroll
    for (int i = 0; i < 4; i++)
      fa[i] = *(const bf16x8*)&ldsA[(wr * 64 + i * 16 + l16) * 32 + quad * 8];
#pragma unroll
    for (int j = 0; j < 4; j++)
      fb[j] = *(const bf16x8*)&ldsB[(wc * 64 + j * 16 + l16) * 32 + quad * 8];

#pragma unroll
    for (int i = 0; i < 4; i++)
#pragma unroll
      for (int j = 0; j < 4; j++)
        acc[i][j] = __builtin_amdgcn_mfma_f32_16x16x32_bf16(fa[i], fb[j], acc[i][j], 0, 0, 0);
  }

#pragma unroll
  for (int i = 0; i < 4; i++) {
    const int row = m0 + wr * 64 + i * 16 + quad * 4;
#pragma unroll
    for (int j = 0; j < 4; j++) {
      const int col = n0 + wc * 64 + j * 16 + l16;
      const float bv2 = bias[col];
#pragma unroll
      for (int r = 0; r < 4; r++)
        Cmat[(size_t)(row + r) * CDIM + col] = acc[i][j][r] + bv2;
    }
  }
}

// ---------------------------------------------------------------------------
// MFMA causal flash attention, v10 = v7 (VERIFIED: 76.4µs, absmax 0.015625,
// 0 bank conflicts) + CU load-balance remap (ran inside passing v8).
// R6 post-mortem: the barrier-free direct-global K/V family (v9/v9.1) is
// ABANDONED — v9.1 produced absmax 495 and the R4/R5 container failures
// were likely the same family; the defect was not locatable by inspection
// (all fragment mappings/bounds verified on paper). Reverting to the last
// verified structure.
// Remap: blocks (id, id+256) co-resident on a CU gave p-pairs (p,p+4) with
// per-CU KT sums 56/52/48/44 (makespan = 56). p = pr<4 ? pr : 11-pr pairs
// (0,7),(1,6),(2,5),(3,4) -> 50/50/50/50. Bijective over p => coverage of
// (bh, j) unchanged; correctness-neutral by construction.
// v7 structure: conflict-free XOR-swizzled LDS, all swizzle math hoisted
// (kt-invariant read bases rb_ks0/1, P-write offsets pwoff[r][nt], staging
// st0/st1); K/V double-buffered reg-staged; ONE barrier per kt.
// LDS = 16+16+32 = 64 KB, 2 blocks/CU.
// ---------------------------------------------------------------------------
__global__ __launch_bounds__(256, 2) void flash_attn_mfma(
    const unsigned short* __restrict__ Qb, const unsigned short* __restrict__ Kb,
    const unsigned short* __restrict__ vt, unsigned short* __restrict__ aout) {
  __shared__ unsigned short K_lds[2 * 64 * 64];     // double-buffered
  __shared__ unsigned short V_lds[2 * 64 * 64];     // double-buffered
  __shared__ unsigned short P_lds[4][2][32 * 64];   // [wave][group][32 rows]

  const int tid  = threadIdx.x;
  const int lane = tid & 63;
  const int wave = tid >> 6;          // 0..3
  const int id   = blockIdx.x;
  const int bh   = id & 63;           // XCD bucket; blocks id,id+256 share bh
  const int pr   = id >> 6;           // 0..7 raw
  const int p    = pr < 4 ? pr : 11 - pr;   // balance remap: pairs sum 50/50/50/50
  const int b    = bh >> 4, h = bh & 15;
  const int quad = lane >> 4;
  const int l16  = lane & 15;

  const int j    = p * 4 + wave;      // 0..31
  const int wqA  = j * 32;
  const int wqB  = (63 - j) * 32;
  const int endA = (wqA >> 6) + 1;    // active tiles for group A
  const int endB = (wqB >> 6) + 1;
  const int KT   = ((63 - 4 * p) >> 1) + 1;   // block-uniform iterations

  // ---- hoisted swizzle bases (kt-invariant) ----
  // read side: phys(row=X*16+l16, col=ks*32+quad*8) = X*1024 + rb_ks
  const int cx34   = (quad * 8) ^ ((l16 & 3) << 3);          // bits 3-4
  const int rb_ks0 = l16 * 64 + ((l16 & 4) << 3) + cx34;     // ks=0
  const int rb_ks1 = l16 * 64 + (32 ^ ((l16 & 4) << 3)) + cx34;  // ks=1
  // P write side: phys(prow=mt*16+quad*4+r, pcol=nt*16+l16) = mt*1024 + pwoff[r][nt]
  int pwoff[4][4];
#pragma unroll
  for (int r = 0; r < 4; r++)
#pragma unroll
    for (int nt = 0; nt < 4; nt++)
      pwoff[r][nt] = (quad * 4 + r) * 64
                   + ((nt * 16) ^ (((quad & 1) << 5) | ((r & 2) << 3)))
                   + (l16 ^ ((r & 1) << 3));
  // staging write side
  const int srow = tid >> 2;          // 0..63
  const int scol = (tid & 3) * 16;    // 0,16,32,48
  const int ms   = (srow & 7) << 3;
  const int st0  = srow * 64 + (scol ^ ms);
  const int st1  = srow * 64 + ((scol + 8) ^ ms);

  // Q A-frags for both groups (Q pre-scaled by 0.125*log2e)
  bf16x8 aqA[2][2], aqB[2][2];
#pragma unroll
  for (int mt = 0; mt < 2; mt++)
#pragma unroll
    for (int ks = 0; ks < 2; ks++) {
      aqA[mt][ks] = *(const bf16x8*)(Qb + (size_t)(b * TSEQ + wqA + mt * 16 + l16) * CDIM
                                        + h * 64 + ks * 32 + quad * 8);
      aqB[mt][ks] = *(const bf16x8*)(Qb + (size_t)(b * TSEQ + wqB + mt * 16 + l16) * CDIM
                                        + h * 64 + ks * 32 + quad * 8);
    }

  f32x4 OA[2][4] = {}, OB[2][4] = {};
  f32x4 lA[2] = {}, lB[2] = {};

  bf16x8 ones;
#pragma unroll
  for (int jj = 0; jj < 8; jj++) ones[jj] = (__bf16)1.0f;

  const unsigned short* Kg = Kb + (size_t)b * TSEQ * CDIM + h * 64;
  const unsigned short* Vg = vt + (size_t)bh * 64 * TSEQ;
  unsigned short* pwA = &P_lds[wave][0][0];
  unsigned short* pwB = &P_lds[wave][1][0];

  // preload tile 0 into staging registers
  uint4 kr0, kr1, vr0, vr1;
  {
    const uint4* ks_ = (const uint4*)(Kg + (size_t)srow * CDIM + scol);
    kr0 = ks_[0]; kr1 = ks_[1];
    const uint4* vs_ = (const uint4*)(Vg + (size_t)srow * TSEQ + scol);
    vr0 = vs_[0]; vr1 = vs_[1];
  }

  for (int kt = 0; kt < KT; kt++) {
    const int kbase = kt * 64;
    const int bo    = (kt & 1) << 12;    // double-buffer offset (u16 units)

    // store staged tile (disjoint from any lagging wave's compute buffer)
    *(uint4*)&K_lds[bo + st0] = kr0;
    *(uint4*)&K_lds[bo + st1] = kr1;
    *(uint4*)&V_lds[bo + st0] = vr0;
    *(uint4*)&V_lds[bo + st1] = vr1;
    __syncthreads();   // staged tile visible; ONE barrier per iteration

    // prefetch next tile: lands during ~2000 cyc of compute
    if (kt + 1 < KT) {
      const uint4* ks_ = (const uint4*)(Kg + (size_t)(kbase + 64 + srow) * CDIM + scol);
      kr0 = ks_[0]; kr1 = ks_[1];
      const uint4* vs_ = (const uint4*)(Vg + (size_t)srow * TSEQ + kbase + 64 + scol);
      vr0 = vs_[0]; vr1 = vs_[1];
    }

    const bool dA = (kt < endA);
    const bool dB = (kt < endB);

    // ---- S phase (both groups) ----
    f32x4 SA[2][4] = {}, SB[2][4] = {};
#pragma unroll
    for (int nt = 0; nt < 4; nt++)
#pragma unroll
      for (int ks = 0; ks < 2; ks++) {
        bf16x8 bk = *(const bf16x8*)&K_lds[bo + nt * 1024 + (ks ? rb_ks1 : rb_ks0)];
        if (dA) {
          SA[0][nt] = __builtin_amdgcn_mfma_f32_16x16x32_bf16(aqA[0][ks], bk, SA[0][nt], 0, 0, 0);
          SA[1][nt] = __builtin_amdgcn_mfma_f32_16x16x32_bf16(aqA[1][ks], bk, SA[1][nt], 0, 0, 0);
        }
        if (dB) {
          SB[0][nt] = __builtin_amdgcn_mfma_f32_16x16x32_bf16(aqB[0][ks], bk, SB[0][nt], 0, 0, 0);
          SB[1][nt] = __builtin_amdgcn_mfma_f32_16x16x32_bf16(aqB[1][ks], bk, SB[1][nt], 0, 0, 0);
        }
      }

    // ---- P phase (exp2; mask only on diagonal tiles) ----
    if (dA) {
      const bool maskedA = (kbase + 64 > wqA);
#pragma unroll
      for (int mt = 0; mt < 2; mt++) {
#pragma unroll
        for (int nt = 0; nt < 4; nt++)
#pragma unroll
          for (int r = 0; r < 4; r += 2) {
            float s0 = SA[mt][nt][r], s1 = SA[mt][nt][r + 1];
            if (maskedA) {
              const int qrow = wqA + mt * 16 + quad * 4 + r;
              const int key  = kbase + nt * 16 + l16;
              s0 = (key <= qrow)     ? s0 : -1e30f;
              s1 = (key <= qrow + 1) ? s1 : -1e30f;
            }
            __hip_bfloat162 p2 = __float22bfloat162_rn(make_float2(EXP2F(s0), EXP2F(s1)));
            unsigned int u; __builtin_memcpy(&u, &p2, 4);
            pwA[pwoff[r    ][nt] + mt * 1024] = (unsigned short)u;
            pwA[pwoff[r + 1][nt] + mt * 1024] = (unsigned short)(u >> 16);
          }
      }
    }
    if (dB) {
      const bool maskedB = (kbase + 64 > wqB);
#pragma unroll
      for (int mt = 0; mt < 2; mt++) {
#pragma unroll
        for (int nt = 0; nt < 4; nt++)
#pragma unroll
          for (int r = 0; r < 4; r += 2) {
            float s0 = SB[mt][nt][r], s1 = SB[mt][nt][r + 1];
            if (maskedB) {
              const int qrow = wqB + mt * 16 + quad * 4 + r;
              const int key  = kbase + nt * 16 + l16;
              s0 = (key <= qrow)     ? s0 : -1e30f;
              s1 = (key <= qrow + 1) ? s1 : -1e30f;
            }
            __hip_bfloat162 p2 = __float22bfloat162_rn(make_float2(EXP2F(s0), EXP2F(s1)));
            unsigned int u; __builtin_memcpy(&u, &p2, 4);
            pwB[pwoff[r    ][nt] + mt * 1024] = (unsigned short)u;
            pwB[pwoff[r + 1][nt] + mt * 1024] = (unsigned short)(u >> 16);
          }
      }
    }

    // ---- O phase (both groups) ----
#pragma unroll
    for (int ks = 0; ks < 2; ks++) {
      const int rb = ks ? rb_ks1 : rb_ks0;
      bf16x8 bv[4];
#pragma unroll
      for (int nt = 0; nt < 4; nt++)
        bv[nt] = *(const bf16x8*)&V_lds[bo + nt * 1024 + rb];
      if (dA) {
#pragma unroll
        for (int mt = 0; mt < 2; mt++) {
          bf16x8 ap = *(const bf16x8*)&pwA[mt * 1024 + rb];
          lA[mt] = __builtin_amdgcn_mfma_f32_16x16x32_bf16(ap, ones, lA[mt], 0, 0, 0);
#pragma unroll
          for (int nt = 0; nt < 4; nt++)
            OA[mt][nt] = __builtin_amdgcn_mfma_f32_16x16x32_bf16(ap, bv[nt], OA[mt][nt], 0, 0, 0);
        }
      }
      if (dB) {
#pragma unroll
        for (int mt = 0; mt < 2; mt++) {
          bf16x8 ap = *(const bf16x8*)&pwB[mt * 1024 + rb];
          lB[mt] = __builtin_amdgcn_mfma_f32_16x16x32_bf16(ap, ones, lB[mt], 0, 0, 0);
#pragma unroll
          for (int nt = 0; nt < 4; nt++)
            OB[mt][nt] = __builtin_amdgcn_mfma_f32_16x16x32_bf16(ap, bv[nt], OB[mt][nt], 0, 0, 0);
        }
      }
    }
  }

  // epilogue: O / l -> aout [b t][h d], both groups
#pragma unroll
  for (int mt = 0; mt < 2; mt++) {
    float invA[4], invB[4];
#pragma unroll
    for (int r = 0; r < 4; r++) { invA[r] = 1.0f / lA[mt][r]; invB[r] = 1.0f / lB[mt][r]; }
    unsigned short* oa = aout + (size_t)(b * TSEQ + wqA + mt * 16 + quad * 4) * CDIM + h * 64 + l16;
    unsigned short* ob = aout + (size_t)(b * TSEQ + wqB + mt * 16 + quad * 4) * CDIM + h * 64 + l16;
#pragma unroll
    for (int nt = 0; nt < 4; nt++)
#pragma unroll
      for (int r = 0; r < 4; r++) {
        oa[(size_t)r * CDIM + nt * 16] = f2bf(OA[mt][nt][r] * invA[r]);
        ob[(size_t)r * CDIM + nt * 16] = f2bf(OB[mt][nt][r] * invB[r]);
      }
  }
}

// ---------------------------------------------------------------------------
extern "C" void kernel_launch(void* const* d_in, const int* in_sizes, int n_in,
                              void* d_out, int out_size, void* d_ws, size_t ws_size,
                              hipStream_t stream) {
  (void)in_sizes; (void)n_in; (void)out_size;
  const float* x     = (const float*)d_in[0];  // [8192,1024] fp32
  const float* w_qkv = (const float*)d_in[1];  // [1024,3072] fp32
  const float* w_out = (const float*)d_in[2];  // [1024,1024] fp32
  const float* b_out = (const float*)d_in[3];  // [1024] fp32
  float* out = (float*)d_out;                  // [8192,1024] fp32

  // Workspace: exactly 72 MiB (proven footprint).
  const size_t WS_NEED = 75497472;
  if (ws_size < WS_NEED) return;

  char* ws = (char*)d_ws;
  unsigned short* Qb    = (unsigned short*)(ws);
  unsigned short* Kb    = (unsigned short*)(ws + 16777216);
  unsigned short* Vb    = (unsigned short*)(ws + 33554432);
  unsigned short* aout  = (unsigned short*)(ws + 33554432);  // alias of Vb
  unsigned short* vt    = (unsigned short*)(ws + 50331648);
  unsigned short* xb    = (unsigned short*)(ws + 50331648);  // alias of vt
  unsigned short* wqkvT = (unsigned short*)(ws + 67108864);
  unsigned short* woutT = (unsigned short*)(ws + 73400320);

  // 1) x -> bf16 (xb, dead after gemm_qkv); weights -> B^T bf16
  cast_f32_bf16<<<MROWS * CDIM / 2048, 256, 0, stream>>>(x, xb, MROWS * CDIM);
  transpose_cast<<<dim3(QKVCOL / 64, CDIM / 64), 256, 0, stream>>>(w_qkv, wqkvT, CDIM, QKVCOL);
  transpose_cast<<<dim3(CDIM / 64, CDIM / 64), 256, 0, stream>>>(w_out, woutT, CDIM, CDIM);

  // 2) QKV projection (Q pre-scaled 0.125*log2e)
  gemm_qkv<<<dim3(QKVCOL / 128, MROWS / 128), 256, 0, stream>>>(xb, wqkvT, Qb, Kb, Vb);

  // 3) V -> V^T per (b,h)   (vt overwrites xb — xb dead)
  transpose_v<<<dim3(TSEQ / 64, BATCH * NHEAD), 256, 0, stream>>>(Vb, vt);

  // 4) balanced block-shared MFMA flash attention -> aout (overwrites Vb)
  flash_attn_mfma<<<dim3(8 * 64), 256, 0, stream>>>(Qb, Kb, vt, aout);

  // 5) out-projection + bias
  gemm_out<<<dim3(CDIM / 128, MROWS / 128), 256, 0, stream>>>(aout, woutT, out, b_out);
}

// Round 8
// 263.420 us; speedup vs baseline: 1.0371x; 1.0122x over previous
//
#include <hip/hip_runtime.h>
#include <hip/hip_bf16.h>

// Shapes (fixed by the problem)
#define BATCH  4
#define TSEQ   2048
#define CDIM   1024
#define NHEAD  16
#define DHEAD  64
#define MROWS  (BATCH * TSEQ)      // 8192
#define QKVCOL (3 * CDIM)          // 3072

typedef __bf16 bf16x8 __attribute__((ext_vector_type(8)));
typedef float  f32x4  __attribute__((ext_vector_type(4)));

// hardware exp2 (v_exp_f32). __exp2f collides with a glibc macro (R12).
#define EXP2F(x) __builtin_amdgcn_exp2f(x)

__device__ __forceinline__ unsigned short f2bf(float f) {
  union { float f; unsigned int i; } v; v.f = f;
  unsigned int i = v.i;
  return (unsigned short)((i + 0x7fffu + ((i >> 16) & 1u)) >> 16);  // RNE
}

__device__ __forceinline__ void load16_to_lds(const void* g, void* l) {
  __builtin_amdgcn_global_load_lds(
      (const __attribute__((address_space(1))) unsigned int*)g,
      (__attribute__((address_space(3))) unsigned int*)l, 16, 0, 0);
}

// ---------------------------------------------------------------------------
// Elementwise cast fp32 -> bf16
// ---------------------------------------------------------------------------
__global__ __launch_bounds__(256) void cast_f32_bf16(
    const float* __restrict__ in, unsigned short* __restrict__ out, int n) {
  const int i = (blockIdx.x * 256 + threadIdx.x) * 8;
  if (i >= n) return;
  float4 a = *(const float4*)(in + i);
  float4 b = *(const float4*)(in + i + 4);
  unsigned short v[8] = {f2bf(a.x), f2bf(a.y), f2bf(a.z), f2bf(a.w),
                         f2bf(b.x), f2bf(b.y), f2bf(b.z), f2bf(b.w)};
  *(uint4*)(out + i) = *(const uint4*)v;
}

// ---------------------------------------------------------------------------
// Fused transpose + cast: fp32 [R,C] -> bf16 [C,R]
// ---------------------------------------------------------------------------
__global__ __launch_bounds__(256) void transpose_cast(
    const float* __restrict__ in, unsigned short* __restrict__ out,
    int R, int C) {
  __shared__ float tile[64][68];
  const int t  = threadIdx.x;
  const int r0 = blockIdx.y * 64;
  const int c0 = blockIdx.x * 64;
  const int tr = t >> 2;
  const int tc = (t & 3) * 16;

  const float4* src = (const float4*)(in + (size_t)(r0 + tr) * C + c0 + tc);
#pragma unroll
  for (int i = 0; i < 4; i++)
    *(float4*)&tile[tr][tc + 4 * i] = src[i];
  __syncthreads();

  unsigned short vals[16];
#pragma unroll
  for (int k = 0; k < 16; k++) vals[k] = f2bf(tile[tc + k][tr]);
  uint4* dst = (uint4*)(out + (size_t)(c0 + tr) * R + r0 + tc);
  dst[0] = ((const uint4*)vals)[0];
  dst[1] = ((const uint4*)vals)[1];
}

// ---------------------------------------------------------------------------
// Transpose bf16 V: Vb [B*T,1024]=[b t][h d] -> vt [b h][d=64][T=2048]
// ---------------------------------------------------------------------------
__global__ __launch_bounds__(256) void transpose_v(
    const unsigned short* __restrict__ Vb, unsigned short* __restrict__ vt) {
  __shared__ unsigned short tile[64][72];
  const int t  = threadIdx.x;
  const int kt = blockIdx.x;
  const int bh = blockIdx.y;
  const int b  = bh >> 4, h = bh & 15;
  const int tr = t >> 2;
  const int tc = (t & 3) * 16;

  const unsigned short* src = Vb + (size_t)(b * TSEQ + kt * 64 + tr) * CDIM + h * 64 + tc;
  *(uint4*)&tile[tr][tc + 0] = ((const uint4*)src)[0];
  *(uint4*)&tile[tr][tc + 8] = ((const uint4*)src)[1];
  __syncthreads();

  unsigned short vals[16];
#pragma unroll
  for (int k = 0; k < 16; k++) vals[k] = tile[tc + k][tr];
  unsigned short* dst = vt + ((size_t)bh * 64 + tr) * TSEQ + kt * 64 + tc;
  ((uint4*)dst)[0] = ((const uint4*)vals)[0];
  ((uint4*)dst)[1] = ((const uint4*)vals)[1];
}

// ---------------------------------------------------------------------------
// QKV GEMM, BK=64 (R7): halves barrier count vs BK=32 (the m97-structure's
// dominant ~20% stall is the vmcnt(0)+lgkmcnt(0) drain at each barrier; 32
// MFMA per drain instead of 16). BK=64 rows = 128B = naive 32-way bank
// conflict (G4), fixed with the v7-verified XOR swizzle (HW-measured 0
// conflicts): linear LDS dest for global_load_lds + PRE-SWIZZLED global
// source col ^= (row&7)*8 (rule #21 both-sides pattern) + hoisted read
// bases rb0/rb1 (bit-identical to v7's rb_ks0/1). Accumulation order per
// (i,j) stays (k0, k0+32) -> bit-exact vs BK=32. LDS 32KB.
// Q scaled by 0.125*log2(e) for exp2 path.
// ---------------------------------------------------------------------------
__global__ __launch_bounds__(256) void gemm_qkv(
    const unsigned short* __restrict__ A, const unsigned short* __restrict__ Bt,
    unsigned short* __restrict__ Qb, unsigned short* __restrict__ Kb,
    unsigned short* __restrict__ Vb) {
  __shared__ unsigned short ldsA[128 * 64];
  __shared__ unsigned short ldsB[128 * 64];

  const int tid  = threadIdx.x;
  const int lane = tid & 63;
  const int wave = tid >> 6;
  const int m0   = blockIdx.y * 128;
  const int n0   = blockIdx.x * 128;
  const int wr   = wave >> 1;
  const int wc   = wave & 1;
  const int quad = lane >> 4;
  const int l16  = lane & 15;

  f32x4 acc[4][4] = {};
  const int rsub = lane >> 3;          // 0..7   (row within 8-row chunk)
  const int csub = (lane & 7) * 8;     // 0..56  (col granule)

  // hoisted conflict-free read bases (v7 formulas, 64-elem rows)
  const int cx34 = (quad * 8) ^ ((l16 & 3) << 3);
  const int rb0  = l16 * 64 + ((l16 & 4) << 3) + cx34;          // ks=0
  const int rb1  = l16 * 64 + (32 ^ ((l16 & 4) << 3)) + cx34;   // ks=1

  for (int k0 = 0; k0 < CDIM; k0 += 64) {
    __syncthreads();
#pragma unroll
    for (int i = 0; i < 4; i++) {
      const int rowbase = i * 32 + wave * 8;
      const int row  = rowbase + rsub;
      const int colS = csub ^ ((row & 7) * 8);   // pre-swizzled source
      load16_to_lds(A  + (size_t)(m0 + row) * CDIM + k0 + colS, &ldsA[rowbase * 64]);
      load16_to_lds(Bt + (size_t)(n0 + row) * CDIM + k0 + colS, &ldsB[rowbase * 64]);
    }
    __syncthreads();

    bf16x8 fa[4][2], fb[4][2];
#pragma unroll
    for (int i = 0; i < 4; i++) {
      fa[i][0] = *(const bf16x8*)&ldsA[wr * 4096 + i * 1024 + rb0];
      fa[i][1] = *(const bf16x8*)&ldsA[wr * 4096 + i * 1024 + rb1];
    }
#pragma unroll
    for (int j = 0; j < 4; j++) {
      fb[j][0] = *(const bf16x8*)&ldsB[wc * 4096 + j * 1024 + rb0];
      fb[j][1] = *(const bf16x8*)&ldsB[wc * 4096 + j * 1024 + rb1];
    }

#pragma unroll
    for (int i = 0; i < 4; i++)
#pragma unroll
      for (int j = 0; j < 4; j++) {
        acc[i][j] = __builtin_amdgcn_mfma_f32_16x16x32_bf16(fa[i][0], fb[j][0], acc[i][j], 0, 0, 0);
        acc[i][j] = __builtin_amdgcn_mfma_f32_16x16x32_bf16(fa[i][1], fb[j][1], acc[i][j], 0, 0, 0);
      }
  }

  const int seg = n0 >> 10;                       // 0=Q 1=K 2=V
  unsigned short* dst = seg == 0 ? Qb : (seg == 1 ? Kb : Vb);
  const float scl = seg == 0 ? 0.18033688f : 1.0f;  // 0.125*log2(e)
#pragma unroll
  for (int i = 0; i < 4; i++) {
    const int row = m0 + wr * 64 + i * 16 + quad * 4;
#pragma unroll
    for (int j = 0; j < 4; j++) {
      const int col = ((n0 & 1023) + wc * 64 + j * 16 + l16);
#pragma unroll
      for (int r = 0; r < 4; r++)
        dst[(size_t)(row + r) * CDIM + col] = f2bf(acc[i][j][r] * scl);
    }
  }
}

// ---------------------------------------------------------------------------
// Out-projection GEMM, BK=64 (same R7 treatment as gemm_qkv).
// ---------------------------------------------------------------------------
__global__ __launch_bounds__(256) void gemm_out(
    const unsigned short* __restrict__ A, const unsigned short* __restrict__ Bt,
    float* __restrict__ Cmat, const float* __restrict__ bias) {
  __shared__ unsigned short ldsA[128 * 64];
  __shared__ unsigned short ldsB[128 * 64];

  const int tid  = threadIdx.x;
  const int lane = tid & 63;
  const int wave = tid >> 6;
  const int m0   = blockIdx.y * 128;
  const int n0   = blockIdx.x * 128;
  const int wr   = wave >> 1;
  const int wc   = wave & 1;
  const int quad = lane >> 4;
  const int l16  = lane & 15;

  f32x4 acc[4][4] = {};
  const int rsub = lane >> 3;
  const int csub = (lane & 7) * 8;

  const int cx34 = (quad * 8) ^ ((l16 & 3) << 3);
  const int rb0  = l16 * 64 + ((l16 & 4) << 3) + cx34;
  const int rb1  = l16 * 64 + (32 ^ ((l16 & 4) << 3)) + cx34;

  for (int k0 = 0; k0 < CDIM; k0 += 64) {
    __syncthreads();
#pragma unroll
    for (int i = 0; i < 4; i++) {
      const int rowbase = i * 32 + wave * 8;
      const int row  = rowbase + rsub;
      const int colS = csub ^ ((row & 7) * 8);
      load16_to_lds(A  + (size_t)(m0 + row) * CDIM + k0 + colS, &ldsA[rowbase * 64]);
      load16_to_lds(Bt + (size_t)(n0 + row) * CDIM + k0 + colS, &ldsB[rowbase * 64]);
    }
    __syncthreads();

    bf16x8 fa[4][2], fb[4][2];
#pragma unroll
    for (int i = 0; i < 4; i++) {
      fa[i][0] = *(const bf16x8*)&ldsA[wr * 4096 + i * 1024 + rb0];
      fa[i][1] = *(const bf16x8*)&ldsA[wr * 4096 + i * 1024 + rb1];
    }
#pragma unroll
    for (int j = 0; j < 4; j++) {
      fb[j][0] = *(const bf16x8*)&ldsB[wc * 4096 + j * 1024 + rb0];
      fb[j][1] = *(const bf16x8*)&ldsB[wc * 4096 + j * 1024 + rb1];
    }

#pragma unroll
    for (int i = 0; i < 4; i++)
#pragma unroll
      for (int j = 0; j < 4; j++) {
        acc[i][j] = __builtin_amdgcn_mfma_f32_16x16x32_bf16(fa[i][0], fb[j][0], acc[i][j], 0, 0, 0);
        acc[i][j] = __builtin_amdgcn_mfma_f32_16x16x32_bf16(fa[i][1], fb[j][1], acc[i][j], 0, 0, 0);
      }
  }

#pragma unroll
  for (int i = 0; i < 4; i++) {
    const int row = m0 + wr * 64 + i * 16 + quad * 4;
#pragma unroll
    for (int j = 0; j < 4; j++) {
      const int col = n0 + wc * 64 + j * 16 + l16;
      const float bv2 = bias[col];
#pragma unroll
      for (int r = 0; r < 4; r++)
        Cmat[(size_t)(row + r) * CDIM + col] = acc[i][j][r] + bv2;
    }
  }
}

// ---------------------------------------------------------------------------
// MFMA causal flash attention, v10 (VERIFIED R7: 75.0µs, absmax 0.015625,
// 0 bank conflicts) = v7 structure + CU load-balance remap. UNCHANGED.
// ---------------------------------------------------------------------------
__global__ __launch_bounds__(256, 2) void flash_attn_mfma(
    const unsigned short* __restrict__ Qb, const unsigned short* __restrict__ Kb,
    const unsigned short* __restrict__ vt, unsigned short* __restrict__ aout) {
  __shared__ unsigned short K_lds[2 * 64 * 64];     // double-buffered
  __shared__ unsigned short V_lds[2 * 64 * 64];     // double-buffered
  __shared__ unsigned short P_lds[4][2][32 * 64];   // [wave][group][32 rows]

  const int tid  = threadIdx.x;
  const int lane = tid & 63;
  const int wave = tid >> 6;          // 0..3
  const int id   = blockIdx.x;
  const int bh   = id & 63;           // XCD bucket; blocks id,id+256 share bh
  const int pr   = id >> 6;           // 0..7 raw
  const int p    = pr < 4 ? pr : 11 - pr;   // balance remap: pairs sum 50/50/50/50
  const int b    = bh >> 4, h = bh & 15;
  const int quad = lane >> 4;
  const int l16  = lane & 15;

  const int j    = p * 4 + wave;      // 0..31
  const int wqA  = j * 32;
  const int wqB  = (63 - j) * 32;
  const int endA = (wqA >> 6) + 1;    // active tiles for group A
  const int endB = (wqB >> 6) + 1;
  const int KT   = ((63 - 4 * p) >> 1) + 1;   // block-uniform iterations

  // ---- hoisted swizzle bases (kt-invariant) ----
  const int cx34   = (quad * 8) ^ ((l16 & 3) << 3);          // bits 3-4
  const int rb_ks0 = l16 * 64 + ((l16 & 4) << 3) + cx34;     // ks=0
  const int rb_ks1 = l16 * 64 + (32 ^ ((l16 & 4) << 3)) + cx34;  // ks=1
  int pwoff[4][4];
#pragma unroll
  for (int r = 0; r < 4; r++)
#pragma unroll
    for (int nt = 0; nt < 4; nt++)
      pwoff[r][nt] = (quad * 4 + r) * 64
                   + ((nt * 16) ^ (((quad & 1) << 5) | ((r & 2) << 3)))
                   + (l16 ^ ((r & 1) << 3));
  // staging write side
  const int srow = tid >> 2;          // 0..63
  const int scol = (tid & 3) * 16;    // 0,16,32,48
  const int ms   = (srow & 7) << 3;
  const int st0  = srow * 64 + (scol ^ ms);
  const int st1  = srow * 64 + ((scol + 8) ^ ms);

  // Q A-frags for both groups (Q pre-scaled by 0.125*log2e)
  bf16x8 aqA[2][2], aqB[2][2];
#pragma unroll
  for (int mt = 0; mt < 2; mt++)
#pragma unroll
    for (int ks = 0; ks < 2; ks++) {
      aqA[mt][ks] = *(const bf16x8*)(Qb + (size_t)(b * TSEQ + wqA + mt * 16 + l16) * CDIM
                                        + h * 64 + ks * 32 + quad * 8);
      aqB[mt][ks] = *(const bf16x8*)(Qb + (size_t)(b * TSEQ + wqB + mt * 16 + l16) * CDIM
                                        + h * 64 + ks * 32 + quad * 8);
    }

  f32x4 OA[2][4] = {}, OB[2][4] = {};
  f32x4 lA[2] = {}, lB[2] = {};

  bf16x8 ones;
#pragma unroll
  for (int jj = 0; jj < 8; jj++) ones[jj] = (__bf16)1.0f;

  const unsigned short* Kg = Kb + (size_t)b * TSEQ * CDIM + h * 64;
  const unsigned short* Vg = vt + (size_t)bh * 64 * TSEQ;
  unsigned short* pwA = &P_lds[wave][0][0];
  unsigned short* pwB = &P_lds[wave][1][0];

  // preload tile 0 into staging registers
  uint4 kr0, kr1, vr0, vr1;
  {
    const uint4* ks_ = (const uint4*)(Kg + (size_t)srow * CDIM + scol);
    kr0 = ks_[0]; kr1 = ks_[1];
    const uint4* vs_ = (const uint4*)(Vg + (size_t)srow * TSEQ + scol);
    vr0 = vs_[0]; vr1 = vs_[1];
  }

  for (int kt = 0; kt < KT; kt++) {
    const int kbase = kt * 64;
    const int bo    = (kt & 1) << 12;    // double-buffer offset (u16 units)

    *(uint4*)&K_lds[bo + st0] = kr0;
    *(uint4*)&K_lds[bo + st1] = kr1;
    *(uint4*)&V_lds[bo + st0] = vr0;
    *(uint4*)&V_lds[bo + st1] = vr1;
    __syncthreads();   // staged tile visible; ONE barrier per iteration

    if (kt + 1 < KT) {
      const uint4* ks_ = (const uint4*)(Kg + (size_t)(kbase + 64 + srow) * CDIM + scol);
      kr0 = ks_[0]; kr1 = ks_[1];
      const uint4* vs_ = (const uint4*)(Vg + (size_t)srow * TSEQ + kbase + 64 + scol);
      vr0 = vs_[0]; vr1 = vs_[1];
    }

    const bool dA = (kt < endA);
    const bool dB = (kt < endB);

    // ---- S phase (both groups) ----
    f32x4 SA[2][4] = {}, SB[2][4] = {};
#pragma unroll
    for (int nt = 0; nt < 4; nt++)
#pragma unroll
      for (int ks = 0; ks < 2; ks++) {
        bf16x8 bk = *(const bf16x8*)&K_lds[bo + nt * 1024 + (ks ? rb_ks1 : rb_ks0)];
        if (dA) {
          SA[0][nt] = __builtin_amdgcn_mfma_f32_16x16x32_bf16(aqA[0][ks], bk, SA[0][nt], 0, 0, 0);
          SA[1][nt] = __builtin_amdgcn_mfma_f32_16x16x32_bf16(aqA[1][ks], bk, SA[1][nt], 0, 0, 0);
        }
        if (dB) {
          SB[0][nt] = __builtin_amdgcn_mfma_f32_16x16x32_bf16(aqB[0][ks], bk, SB[0][nt], 0, 0, 0);
          SB[1][nt] = __builtin_amdgcn_mfma_f32_16x16x32_bf16(aqB[1][ks], bk, SB[1][nt], 0, 0, 0);
        }
      }

    // ---- P phase (exp2; mask only on diagonal tiles) ----
    if (dA) {
      const bool maskedA = (kbase + 64 > wqA);
#pragma unroll
      for (int mt = 0; mt < 2; mt++) {
#pragma unroll
        for (int nt = 0; nt < 4; nt++)
#pragma unroll
          for (int r = 0; r < 4; r += 2) {
            float s0 = SA[mt][nt][r], s1 = SA[mt][nt][r + 1];
            if (maskedA) {
              const int qrow = wqA + mt * 16 + quad * 4 + r;
              const int key  = kbase + nt * 16 + l16;
              s0 = (key <= qrow)     ? s0 : -1e30f;
              s1 = (key <= qrow + 1) ? s1 : -1e30f;
            }
            __hip_bfloat162 p2 = __float22bfloat162_rn(make_float2(EXP2F(s0), EXP2F(s1)));
            unsigned int u; __builtin_memcpy(&u, &p2, 4);
            pwA[pwoff[r    ][nt] + mt * 1024] = (unsigned short)u;
            pwA[pwoff[r + 1][nt] + mt * 1024] = (unsigned short)(u >> 16);
          }
      }
    }
    if (dB) {
      const bool maskedB = (kbase + 64 > wqB);
#pragma unroll
      for (int mt = 0; mt < 2; mt++) {
#pragma unroll
        for (int nt = 0; nt < 4; nt++)
#pragma unroll
          for (int r = 0; r < 4; r += 2) {
            float s0 = SB[mt][nt][r], s1 = SB[mt][nt][r + 1];
            if (maskedB) {
              const int qrow = wqB + mt * 16 + quad * 4 + r;
              const int key  = kbase + nt * 16 + l16;
              s0 = (key <= qrow)     ? s0 : -1e30f;
              s1 = (key <= qrow + 1) ? s1 : -1e30f;
            }
            __hip_bfloat162 p2 = __float22bfloat162_rn(make_float2(EXP2F(s0), EXP2F(s1)));
            unsigned int u; __builtin_memcpy(&u, &p2, 4);
            pwB[pwoff[r    ][nt] + mt * 1024] = (unsigned short)u;
            pwB[pwoff[r + 1][nt] + mt * 1024] = (unsigned short)(u >> 16);
          }
      }
    }

    // ---- O phase (both groups) ----
#pragma unroll
    for (int ks = 0; ks < 2; ks++) {
      const int rb = ks ? rb_ks1 : rb_ks0;
      bf16x8 bv[4];
#pragma unroll
      for (int nt = 0; nt < 4; nt++)
        bv[nt] = *(const bf16x8*)&V_lds[bo + nt * 1024 + rb];
      if (dA) {
#pragma unroll
        for (int mt = 0; mt < 2; mt++) {
          bf16x8 ap = *(const bf16x8*)&pwA[mt * 1024 + rb];
          lA[mt] = __builtin_amdgcn_mfma_f32_16x16x32_bf16(ap, ones, lA[mt], 0, 0, 0);
#pragma unroll
          for (int nt = 0; nt < 4; nt++)
            OA[mt][nt] = __builtin_amdgcn_mfma_f32_16x16x32_bf16(ap, bv[nt], OA[mt][nt], 0, 0, 0);
        }
      }
      if (dB) {
#pragma unroll
        for (int mt = 0; mt < 2; mt++) {
          bf16x8 ap = *(const bf16x8*)&pwB[mt * 1024 + rb];
          lB[mt] = __builtin_amdgcn_mfma_f32_16x16x32_bf16(ap, ones, lB[mt], 0, 0, 0);
#pragma unroll
          for (int nt = 0; nt < 4; nt++)
            OB[mt][nt] = __builtin_amdgcn_mfma_f32_16x16x32_bf16(ap, bv[nt], OB[mt][nt], 0, 0, 0);
        }
      }
    }
  }

  // epilogue: O / l -> aout [b t][h d], both groups
#pragma unroll
  for (int mt = 0; mt < 2; mt++) {
    float invA[4], invB[4];
#pragma unroll
    for (int r = 0; r < 4; r++) { invA[r] = 1.0f / lA[mt][r]; invB[r] = 1.0f / lB[mt][r]; }
    unsigned short* oa = aout + (size_t)(b * TSEQ + wqA + mt * 16 + quad * 4) * CDIM + h * 64 + l16;
    unsigned short* ob = aout + (size_t)(b * TSEQ + wqB + mt * 16 + quad * 4) * CDIM + h * 64 + l16;
#pragma unroll
    for (int nt = 0; nt < 4; nt++)
#pragma unroll
      for (int r = 0; r < 4; r++) {
        oa[(size_t)r * CDIM + nt * 16] = f2bf(OA[mt][nt][r] * invA[r]);
        ob[(size_t)r * CDIM + nt * 16] = f2bf(OB[mt][nt][r] * invB[r]);
      }
  }
}

// ---------------------------------------------------------------------------
extern "C" void kernel_launch(void* const* d_in, const int* in_sizes, int n_in,
                              void* d_out, int out_size, void* d_ws, size_t ws_size,
                              hipStream_t stream) {
  (void)in_sizes; (void)n_in; (void)out_size;
  const float* x     = (const float*)d_in[0];  // [8192,1024] fp32
  const float* w_qkv = (const float*)d_in[1];  // [1024,3072] fp32
  const float* w_out = (const float*)d_in[2];  // [1024,1024] fp32
  const float* b_out = (const float*)d_in[3];  // [1024] fp32
  float* out = (float*)d_out;                  // [8192,1024] fp32

  // Workspace: exactly 72 MiB (proven footprint).
  const size_t WS_NEED = 75497472;
  if (ws_size < WS_NEED) return;

  char* ws = (char*)d_ws;
  unsigned short* Qb    = (unsigned short*)(ws);
  unsigned short* Kb    = (unsigned short*)(ws + 16777216);
  unsigned short* Vb    = (unsigned short*)(ws + 33554432);
  unsigned short* aout  = (unsigned short*)(ws + 33554432);  // alias of Vb
  unsigned short* vt    = (unsigned short*)(ws + 50331648);
  unsigned short* xb    = (unsigned short*)(ws + 50331648);  // alias of vt
  unsigned short* wqkvT = (unsigned short*)(ws + 67108864);
  unsigned short* woutT = (unsigned short*)(ws + 73400320);

  // 1) x -> bf16 (xb, dead after gemm_qkv); weights -> B^T bf16
  cast_f32_bf16<<<MROWS * CDIM / 2048, 256, 0, stream>>>(x, xb, MROWS * CDIM);
  transpose_cast<<<dim3(QKVCOL / 64, CDIM / 64), 256, 0, stream>>>(w_qkv, wqkvT, CDIM, QKVCOL);
  transpose_cast<<<dim3(CDIM / 64, CDIM / 64), 256, 0, stream>>>(w_out, woutT, CDIM, CDIM);

  // 2) QKV projection (Q pre-scaled 0.125*log2e), BK=64 swizzled staging
  gemm_qkv<<<dim3(QKVCOL / 128, MROWS / 128), 256, 0, stream>>>(xb, wqkvT, Qb, Kb, Vb);

  // 3) V -> V^T per (b,h)   (vt overwrites xb — xb dead)
  transpose_v<<<dim3(TSEQ / 64, BATCH * NHEAD), 256, 0, stream>>>(Vb, vt);

  // 4) balanced block-shared MFMA flash attention -> aout (overwrites Vb)
  flash_attn_mfma<<<dim3(8 * 64), 256, 0, stream>>>(Qb, Kb, vt, aout);

  // 5) out-projection + bias, BK=64 swizzled staging
  gemm_out<<<dim3(CDIM / 128, MROWS / 128), 256, 0, stream>>>(aout, woutT, out, b_out);
}

// Round 9
// 256.868 us; speedup vs baseline: 1.0635x; 1.0255x over previous
//
#include <hip/hip_runtime.h>
#include <hip/hip_bf16.h>

// Shapes (fixed by the problem)
#define BATCH  4
#define TSEQ   2048
#define CDIM   1024
#define NHEAD  16
#define DHEAD  64
#define MROWS  (BATCH * TSEQ)      // 8192
#define QKVCOL (3 * CDIM)          // 3072

typedef __bf16 bf16x8 __attribute__((ext_vector_type(8)));
typedef float  f32x4  __attribute__((ext_vector_type(4)));

// hardware exp2 (v_exp_f32). __exp2f collides with a glibc macro (R12).
#define EXP2F(x) __builtin_amdgcn_exp2f(x)

__device__ __forceinline__ unsigned short f2bf(float f) {
  union { float f; unsigned int i; } v; v.f = f;
  unsigned int i = v.i;
  return (unsigned short)((i + 0x7fffu + ((i >> 16) & 1u)) >> 16);  // RNE
}

__device__ __forceinline__ void load16_to_lds(const void* g, void* l) {
  __builtin_amdgcn_global_load_lds(
      (const __attribute__((address_space(1))) unsigned int*)g,
      (__attribute__((address_space(3))) unsigned int*)l, 16, 0, 0);
}

// ---------------------------------------------------------------------------
// Elementwise cast fp32 -> bf16
// ---------------------------------------------------------------------------
__global__ __launch_bounds__(256) void cast_f32_bf16(
    const float* __restrict__ in, unsigned short* __restrict__ out, int n) {
  const int i = (blockIdx.x * 256 + threadIdx.x) * 8;
  if (i >= n) return;
  float4 a = *(const float4*)(in + i);
  float4 b = *(const float4*)(in + i + 4);
  unsigned short v[8] = {f2bf(a.x), f2bf(a.y), f2bf(a.z), f2bf(a.w),
                         f2bf(b.x), f2bf(b.y), f2bf(b.z), f2bf(b.w)};
  *(uint4*)(out + i) = *(const uint4*)v;
}

// ---------------------------------------------------------------------------
// Fused transpose + cast: fp32 [R,C] -> bf16 [C,R]
// ---------------------------------------------------------------------------
__global__ __launch_bounds__(256) void transpose_cast(
    const float* __restrict__ in, unsigned short* __restrict__ out,
    int R, int C) {
  __shared__ float tile[64][68];
  const int t  = threadIdx.x;
  const int r0 = blockIdx.y * 64;
  const int c0 = blockIdx.x * 64;
  const int tr = t >> 2;
  const int tc = (t & 3) * 16;

  const float4* src = (const float4*)(in + (size_t)(r0 + tr) * C + c0 + tc);
#pragma unroll
  for (int i = 0; i < 4; i++)
    *(float4*)&tile[tr][tc + 4 * i] = src[i];
  __syncthreads();

  unsigned short vals[16];
#pragma unroll
  for (int k = 0; k < 16; k++) vals[k] = f2bf(tile[tc + k][tr]);
  uint4* dst = (uint4*)(out + (size_t)(c0 + tr) * R + r0 + tc);
  dst[0] = ((const uint4*)vals)[0];
  dst[1] = ((const uint4*)vals)[1];
}

// ---------------------------------------------------------------------------
// QKV GEMM, BK=64 swizzled staging (verified R8) + R9: V^T FUSED EPILOGUE.
// seg==2 (V) writes directly to vt [b*16+h][d=64][T=2048] — the separate
// transpose_v kernel (33.4 MB round trip + launch) is deleted. Along r,
// t = row+r is contiguous -> 4 bf16 pack into one 8B store (t0 % 4 == 0 so
// 8B-aligned). Values are f2bf(acc) exactly as before (transpose_v only
// copied bits) -> bit-exact vs R8.
// BK=64: halves barrier count vs BK=32; 128B rows conflict-free via the
// v7-verified XOR swizzle (pre-swizzled global source col ^= (row&7)*8,
// linear LDS dest, hoisted read bases rb0/rb1). LDS 32KB.
// Q scaled by 0.125*log2(e) for exp2 path.
// ---------------------------------------------------------------------------
__global__ __launch_bounds__(256) void gemm_qkv(
    const unsigned short* __restrict__ A, const unsigned short* __restrict__ Bt,
    unsigned short* __restrict__ Qb, unsigned short* __restrict__ Kb,
    unsigned short* __restrict__ vt) {
  __shared__ unsigned short ldsA[128 * 64];
  __shared__ unsigned short ldsB[128 * 64];

  const int tid  = threadIdx.x;
  const int lane = tid & 63;
  const int wave = tid >> 6;
  const int m0   = blockIdx.y * 128;
  const int n0   = blockIdx.x * 128;
  const int wr   = wave >> 1;
  const int wc   = wave & 1;
  const int quad = lane >> 4;
  const int l16  = lane & 15;

  f32x4 acc[4][4] = {};
  const int rsub = lane >> 3;          // 0..7   (row within 8-row chunk)
  const int csub = (lane & 7) * 8;     // 0..56  (col granule)

  // hoisted conflict-free read bases (v7 formulas, 64-elem rows)
  const int cx34 = (quad * 8) ^ ((l16 & 3) << 3);
  const int rb0  = l16 * 64 + ((l16 & 4) << 3) + cx34;          // ks=0
  const int rb1  = l16 * 64 + (32 ^ ((l16 & 4) << 3)) + cx34;   // ks=1

  for (int k0 = 0; k0 < CDIM; k0 += 64) {
    __syncthreads();
#pragma unroll
    for (int i = 0; i < 4; i++) {
      const int rowbase = i * 32 + wave * 8;
      const int row  = rowbase + rsub;
      const int colS = csub ^ ((row & 7) * 8);   // pre-swizzled source
      load16_to_lds(A  + (size_t)(m0 + row) * CDIM + k0 + colS, &ldsA[rowbase * 64]);
      load16_to_lds(Bt + (size_t)(n0 + row) * CDIM + k0 + colS, &ldsB[rowbase * 64]);
    }
    __syncthreads();

    bf16x8 fa[4][2], fb[4][2];
#pragma unroll
    for (int i = 0; i < 4; i++) {
      fa[i][0] = *(const bf16x8*)&ldsA[wr * 4096 + i * 1024 + rb0];
      fa[i][1] = *(const bf16x8*)&ldsA[wr * 4096 + i * 1024 + rb1];
    }
#pragma unroll
    for (int j = 0; j < 4; j++) {
      fb[j][0] = *(const bf16x8*)&ldsB[wc * 4096 + j * 1024 + rb0];
      fb[j][1] = *(const bf16x8*)&ldsB[wc * 4096 + j * 1024 + rb1];
    }

#pragma unroll
    for (int i = 0; i < 4; i++)
#pragma unroll
      for (int j = 0; j < 4; j++) {
        acc[i][j] = __builtin_amdgcn_mfma_f32_16x16x32_bf16(fa[i][0], fb[j][0], acc[i][j], 0, 0, 0);
        acc[i][j] = __builtin_amdgcn_mfma_f32_16x16x32_bf16(fa[i][1], fb[j][1], acc[i][j], 0, 0, 0);
      }
  }

  const int seg = n0 >> 10;                       // 0=Q 1=K 2=V
  if (seg == 2) {
    // V: write directly transposed into vt [b*16+h][d][t] (bit-exact values)
#pragma unroll
    for (int i = 0; i < 4; i++) {
      const int row = m0 + wr * 64 + i * 16 + quad * 4;   // = b*2048 + t0
      const int bb  = row >> 11;
      const int t0  = row & 2047;                          // t0 % 4 == 0
#pragma unroll
      for (int j = 0; j < 4; j++) {
        const int col = ((n0 & 1023) + wc * 64 + j * 16 + l16);  // h*64+d
        unsigned short v4[4];
#pragma unroll
        for (int r = 0; r < 4; r++) v4[r] = f2bf(acc[i][j][r]);
        *(uint2*)(vt + ((size_t)(bb * 16 + (col >> 6)) * 64 + (col & 63)) * TSEQ + t0)
            = *(const uint2*)v4;
      }
    }
  } else {
    unsigned short* dst = seg == 0 ? Qb : Kb;
    const float scl = seg == 0 ? 0.18033688f : 1.0f;  // 0.125*log2(e)
#pragma unroll
    for (int i = 0; i < 4; i++) {
      const int row = m0 + wr * 64 + i * 16 + quad * 4;
#pragma unroll
      for (int j = 0; j < 4; j++) {
        const int col = ((n0 & 1023) + wc * 64 + j * 16 + l16);
#pragma unroll
        for (int r = 0; r < 4; r++)
          dst[(size_t)(row + r) * CDIM + col] = f2bf(acc[i][j][r] * scl);
      }
    }
  }
}

// ---------------------------------------------------------------------------
// Out-projection GEMM, BK=64 swizzled staging (verified R8). UNCHANGED.
// ---------------------------------------------------------------------------
__global__ __launch_bounds__(256) void gemm_out(
    const unsigned short* __restrict__ A, const unsigned short* __restrict__ Bt,
    float* __restrict__ Cmat, const float* __restrict__ bias) {
  __shared__ unsigned short ldsA[128 * 64];
  __shared__ unsigned short ldsB[128 * 64];

  const int tid  = threadIdx.x;
  const int lane = tid & 63;
  const int wave = tid >> 6;
  const int m0   = blockIdx.y * 128;
  const int n0   = blockIdx.x * 128;
  const int wr   = wave >> 1;
  const int wc   = wave & 1;
  const int quad = lane >> 4;
  const int l16  = lane & 15;

  f32x4 acc[4][4] = {};
  const int rsub = lane >> 3;
  const int csub = (lane & 7) * 8;

  const int cx34 = (quad * 8) ^ ((l16 & 3) << 3);
  const int rb0  = l16 * 64 + ((l16 & 4) << 3) + cx34;
  const int rb1  = l16 * 64 + (32 ^ ((l16 & 4) << 3)) + cx34;

  for (int k0 = 0; k0 < CDIM; k0 += 64) {
    __syncthreads();
#pragma unroll
    for (int i = 0; i < 4; i++) {
      const int rowbase = i * 32 + wave * 8;
      const int row  = rowbase + rsub;
      const int colS = csub ^ ((row & 7) * 8);
      load16_to_lds(A  + (size_t)(m0 + row) * CDIM + k0 + colS, &ldsA[rowbase * 64]);
      load16_to_lds(Bt + (size_t)(n0 + row) * CDIM + k0 + colS, &ldsB[rowbase * 64]);
    }
    __syncthreads();

    bf16x8 fa[4][2], fb[4][2];
#pragma unroll
    for (int i = 0; i < 4; i++) {
      fa[i][0] = *(const bf16x8*)&ldsA[wr * 4096 + i * 1024 + rb0];
      fa[i][1] = *(const bf16x8*)&ldsA[wr * 4096 + i * 1024 + rb1];
    }
#pragma unroll
    for (int j = 0; j < 4; j++) {
      fb[j][0] = *(const bf16x8*)&ldsB[wc * 4096 + j * 1024 + rb0];
      fb[j][1] = *(const bf16x8*)&ldsB[wc * 4096 + j * 1024 + rb1];
    }

#pragma unroll
    for (int i = 0; i < 4; i++)
#pragma unroll
      for (int j = 0; j < 4; j++) {
        acc[i][j] = __builtin_amdgcn_mfma_f32_16x16x32_bf16(fa[i][0], fb[j][0], acc[i][j], 0, 0, 0);
        acc[i][j] = __builtin_amdgcn_mfma_f32_16x16x32_bf16(fa[i][1], fb[j][1], acc[i][j], 0, 0, 0);
      }
  }

#pragma unroll
  for (int i = 0; i < 4; i++) {
    const int row = m0 + wr * 64 + i * 16 + quad * 4;
#pragma unroll
    for (int j = 0; j < 4; j++) {
      const int col = n0 + wc * 64 + j * 16 + l16;
      const float bv2 = bias[col];
#pragma unroll
      for (int r = 0; r < 4; r++)
        Cmat[(size_t)(row + r) * CDIM + col] = acc[i][j][r] + bv2;
    }
  }
}

// ---------------------------------------------------------------------------
// MFMA causal flash attention, v10 (VERIFIED R7/R8: ~75-76µs, absmax
// 0.015625, 0 bank conflicts) = v7 structure + CU load-balance remap.
// UNCHANGED.
// ---------------------------------------------------------------------------
__global__ __launch_bounds__(256, 2) void flash_attn_mfma(
    const unsigned short* __restrict__ Qb, const unsigned short* __restrict__ Kb,
    const unsigned short* __restrict__ vt, unsigned short* __restrict__ aout) {
  __shared__ unsigned short K_lds[2 * 64 * 64];     // double-buffered
  __shared__ unsigned short V_lds[2 * 64 * 64];     // double-buffered
  __shared__ unsigned short P_lds[4][2][32 * 64];   // [wave][group][32 rows]

  const int tid  = threadIdx.x;
  const int lane = tid & 63;
  const int wave = tid >> 6;          // 0..3
  const int id   = blockIdx.x;
  const int bh   = id & 63;           // XCD bucket; blocks id,id+256 share bh
  const int pr   = id >> 6;           // 0..7 raw
  const int p    = pr < 4 ? pr : 11 - pr;   // balance remap: pairs sum 50/50/50/50
  const int b    = bh >> 4, h = bh & 15;
  const int quad = lane >> 4;
  const int l16  = lane & 15;

  const int j    = p * 4 + wave;      // 0..31
  const int wqA  = j * 32;
  const int wqB  = (63 - j) * 32;
  const int endA = (wqA >> 6) + 1;    // active tiles for group A
  const int endB = (wqB >> 6) + 1;
  const int KT   = ((63 - 4 * p) >> 1) + 1;   // block-uniform iterations

  // ---- hoisted swizzle bases (kt-invariant) ----
  const int cx34   = (quad * 8) ^ ((l16 & 3) << 3);          // bits 3-4
  const int rb_ks0 = l16 * 64 + ((l16 & 4) << 3) + cx34;     // ks=0
  const int rb_ks1 = l16 * 64 + (32 ^ ((l16 & 4) << 3)) + cx34;  // ks=1
  int pwoff[4][4];
#pragma unroll
  for (int r = 0; r < 4; r++)
#pragma unroll
    for (int nt = 0; nt < 4; nt++)
      pwoff[r][nt] = (quad * 4 + r) * 64
                   + ((nt * 16) ^ (((quad & 1) << 5) | ((r & 2) << 3)))
                   + (l16 ^ ((r & 1) << 3));
  // staging write side
  const int srow = tid >> 2;          // 0..63
  const int scol = (tid & 3) * 16;    // 0,16,32,48
  const int ms   = (srow & 7) << 3;
  const int st0  = srow * 64 + (scol ^ ms);
  const int st1  = srow * 64 + ((scol + 8) ^ ms);

  // Q A-frags for both groups (Q pre-scaled by 0.125*log2e)
  bf16x8 aqA[2][2], aqB[2][2];
#pragma unroll
  for (int mt = 0; mt < 2; mt++)
#pragma unroll
    for (int ks = 0; ks < 2; ks++) {
      aqA[mt][ks] = *(const bf16x8*)(Qb + (size_t)(b * TSEQ + wqA + mt * 16 + l16) * CDIM
                                        + h * 64 + ks * 32 + quad * 8);
      aqB[mt][ks] = *(const bf16x8*)(Qb + (size_t)(b * TSEQ + wqB + mt * 16 + l16) * CDIM
                                        + h * 64 + ks * 32 + quad * 8);
    }

  f32x4 OA[2][4] = {}, OB[2][4] = {};
  f32x4 lA[2] = {}, lB[2] = {};

  bf16x8 ones;
#pragma unroll
  for (int jj = 0; jj < 8; jj++) ones[jj] = (__bf16)1.0f;

  const unsigned short* Kg = Kb + (size_t)b * TSEQ * CDIM + h * 64;
  const unsigned short* Vg = vt + (size_t)bh * 64 * TSEQ;
  unsigned short* pwA = &P_lds[wave][0][0];
  unsigned short* pwB = &P_lds[wave][1][0];

  // preload tile 0 into staging registers
  uint4 kr0, kr1, vr0, vr1;
  {
    const uint4* ks_ = (const uint4*)(Kg + (size_t)srow * CDIM + scol);
    kr0 = ks_[0]; kr1 = ks_[1];
    const uint4* vs_ = (const uint4*)(Vg + (size_t)srow * TSEQ + scol);
    vr0 = vs_[0]; vr1 = vs_[1];
  }

  for (int kt = 0; kt < KT; kt++) {
    const int kbase = kt * 64;
    const int bo    = (kt & 1) << 12;    // double-buffer offset (u16 units)

    *(uint4*)&K_lds[bo + st0] = kr0;
    *(uint4*)&K_lds[bo + st1] = kr1;
    *(uint4*)&V_lds[bo + st0] = vr0;
    *(uint4*)&V_lds[bo + st1] = vr1;
    __syncthreads();   // staged tile visible; ONE barrier per iteration

    if (kt + 1 < KT) {
      const uint4* ks_ = (const uint4*)(Kg + (size_t)(kbase + 64 + srow) * CDIM + scol);
      kr0 = ks_[0]; kr1 = ks_[1];
      const uint4* vs_ = (const uint4*)(Vg + (size_t)srow * TSEQ + kbase + 64 + scol);
      vr0 = vs_[0]; vr1 = vs_[1];
    }

    const bool dA = (kt < endA);
    const bool dB = (kt < endB);

    // ---- S phase (both groups) ----
    f32x4 SA[2][4] = {}, SB[2][4] = {};
#pragma unroll
    for (int nt = 0; nt < 4; nt++)
#pragma unroll
      for (int ks = 0; ks < 2; ks++) {
        bf16x8 bk = *(const bf16x8*)&K_lds[bo + nt * 1024 + (ks ? rb_ks1 : rb_ks0)];
        if (dA) {
          SA[0][nt] = __builtin_amdgcn_mfma_f32_16x16x32_bf16(aqA[0][ks], bk, SA[0][nt], 0, 0, 0);
          SA[1][nt] = __builtin_amdgcn_mfma_f32_16x16x32_bf16(aqA[1][ks], bk, SA[1][nt], 0, 0, 0);
        }
        if (dB) {
          SB[0][nt] = __builtin_amdgcn_mfma_f32_16x16x32_bf16(aqB[0][ks], bk, SB[0][nt], 0, 0, 0);
          SB[1][nt] = __builtin_amdgcn_mfma_f32_16x16x32_bf16(aqB[1][ks], bk, SB[1][nt], 0, 0, 0);
        }
      }

    // ---- P phase (exp2; mask only on diagonal tiles) ----
    if (dA) {
      const bool maskedA = (kbase + 64 > wqA);
#pragma unroll
      for (int mt = 0; mt < 2; mt++) {
#pragma unroll
        for (int nt = 0; nt < 4; nt++)
#pragma unroll
          for (int r = 0; r < 4; r += 2) {
            float s0 = SA[mt][nt][r], s1 = SA[mt][nt][r + 1];
            if (maskedA) {
              const int qrow = wqA + mt * 16 + quad * 4 + r;
              const int key  = kbase + nt * 16 + l16;
              s0 = (key <= qrow)     ? s0 : -1e30f;
              s1 = (key <= qrow + 1) ? s1 : -1e30f;
            }
            __hip_bfloat162 p2 = __float22bfloat162_rn(make_float2(EXP2F(s0), EXP2F(s1)));
            unsigned int u; __builtin_memcpy(&u, &p2, 4);
            pwA[pwoff[r    ][nt] + mt * 1024] = (unsigned short)u;
            pwA[pwoff[r + 1][nt] + mt * 1024] = (unsigned short)(u >> 16);
          }
      }
    }
    if (dB) {
      const bool maskedB = (kbase + 64 > wqB);
#pragma unroll
      for (int mt = 0; mt < 2; mt++) {
#pragma unroll
        for (int nt = 0; nt < 4; nt++)
#pragma unroll
          for (int r = 0; r < 4; r += 2) {
            float s0 = SB[mt][nt][r], s1 = SB[mt][nt][r + 1];
            if (maskedB) {
              const int qrow = wqB + mt * 16 + quad * 4 + r;
              const int key  = kbase + nt * 16 + l16;
              s0 = (key <= qrow)     ? s0 : -1e30f;
              s1 = (key <= qrow + 1) ? s1 : -1e30f;
            }
            __hip_bfloat162 p2 = __float22bfloat162_rn(make_float2(EXP2F(s0), EXP2F(s1)));
            unsigned int u; __builtin_memcpy(&u, &p2, 4);
            pwB[pwoff[r    ][nt] + mt * 1024] = (unsigned short)u;
            pwB[pwoff[r + 1][nt] + mt * 1024] = (unsigned short)(u >> 16);
          }
      }
    }

    // ---- O phase (both groups) ----
#pragma unroll
    for (int ks = 0; ks < 2; ks++) {
      const int rb = ks ? rb_ks1 : rb_ks0;
      bf16x8 bv[4];
#pragma unroll
      for (int nt = 0; nt < 4; nt++)
        bv[nt] = *(const bf16x8*)&V_lds[bo + nt * 1024 + rb];
      if (dA) {
#pragma unroll
        for (int mt = 0; mt < 2; mt++) {
          bf16x8 ap = *(const bf16x8*)&pwA[mt * 1024 + rb];
          lA[mt] = __builtin_amdgcn_mfma_f32_16x16x32_bf16(ap, ones, lA[mt], 0, 0, 0);
#pragma unroll
          for (int nt = 0; nt < 4; nt++)
            OA[mt][nt] = __builtin_amdgcn_mfma_f32_16x16x32_bf16(ap, bv[nt], OA[mt][nt], 0, 0, 0);
        }
      }
      if (dB) {
#pragma unroll
        for (int mt = 0; mt < 2; mt++) {
          bf16x8 ap = *(const bf16x8*)&pwB[mt * 1024 + rb];
          lB[mt] = __builtin_amdgcn_mfma_f32_16x16x32_bf16(ap, ones, lB[mt], 0, 0, 0);
#pragma unroll
          for (int nt = 0; nt < 4; nt++)
            OB[mt][nt] = __builtin_amdgcn_mfma_f32_16x16x32_bf16(ap, bv[nt], OB[mt][nt], 0, 0, 0);
        }
      }
    }
  }

  // epilogue: O / l -> aout [b t][h d], both groups
#pragma unroll
  for (int mt = 0; mt < 2; mt++) {
    float invA[4], invB[4];
#pragma unroll
    for (int r = 0; r < 4; r++) { invA[r] = 1.0f / lA[mt][r]; invB[r] = 1.0f / lB[mt][r]; }
    unsigned short* oa = aout + (size_t)(b * TSEQ + wqA + mt * 16 + quad * 4) * CDIM + h * 64 + l16;
    unsigned short* ob = aout + (size_t)(b * TSEQ + wqB + mt * 16 + quad * 4) * CDIM + h * 64 + l16;
#pragma unroll
    for (int nt = 0; nt < 4; nt++)
#pragma unroll
      for (int r = 0; r < 4; r++) {
        oa[(size_t)r * CDIM + nt * 16] = f2bf(OA[mt][nt][r] * invA[r]);
        ob[(size_t)r * CDIM + nt * 16] = f2bf(OB[mt][nt][r] * invB[r]);
      }
  }
}

// ---------------------------------------------------------------------------
extern "C" void kernel_launch(void* const* d_in, const int* in_sizes, int n_in,
                              void* d_out, int out_size, void* d_ws, size_t ws_size,
                              hipStream_t stream) {
  (void)in_sizes; (void)n_in; (void)out_size;
  const float* x     = (const float*)d_in[0];  // [8192,1024] fp32
  const float* w_qkv = (const float*)d_in[1];  // [1024,3072] fp32
  const float* w_out = (const float*)d_in[2];  // [1024,1024] fp32
  const float* b_out = (const float*)d_in[3];  // [1024] fp32
  float* out = (float*)d_out;                  // [8192,1024] fp32

  // Workspace: 72 MiB. R9 layout (V^T fused into gemm_qkv):
  //   Qb@0, Kb@16M, vt@32M (written by gemm_qkv, read by flash),
  //   xb@48M (input A, dead after gemm_qkv), aout@48M (aliases xb),
  //   wqkvT@64M, woutT@70M.
  const size_t WS_NEED = 75497472;
  if (ws_size < WS_NEED) return;

  char* ws = (char*)d_ws;
  unsigned short* Qb    = (unsigned short*)(ws);
  unsigned short* Kb    = (unsigned short*)(ws + 16777216);
  unsigned short* vt    = (unsigned short*)(ws + 33554432);
  unsigned short* xb    = (unsigned short*)(ws + 50331648);
  unsigned short* aout  = (unsigned short*)(ws + 50331648);  // alias of xb
  unsigned short* wqkvT = (unsigned short*)(ws + 67108864);
  unsigned short* woutT = (unsigned short*)(ws + 73400320);

  // 1) x -> bf16 (xb, dead after gemm_qkv); weights -> B^T bf16
  cast_f32_bf16<<<MROWS * CDIM / 2048, 256, 0, stream>>>(x, xb, MROWS * CDIM);
  transpose_cast<<<dim3(QKVCOL / 64, CDIM / 64), 256, 0, stream>>>(w_qkv, wqkvT, CDIM, QKVCOL);
  transpose_cast<<<dim3(CDIM / 64, CDIM / 64), 256, 0, stream>>>(w_out, woutT, CDIM, CDIM);

  // 2) QKV projection (Q pre-scaled 0.125*log2e); V written directly as vt
  gemm_qkv<<<dim3(QKVCOL / 128, MROWS / 128), 256, 0, stream>>>(xb, wqkvT, Qb, Kb, vt);

  // 3) balanced block-shared MFMA flash attention -> aout (overwrites xb)
  flash_attn_mfma<<<dim3(8 * 64), 256, 0, stream>>>(Qb, Kb, vt, aout);

  // 4) out-projection + bias
  gemm_out<<<dim3(CDIM / 128, MROWS / 128), 256, 0, stream>>>(aout, woutT, out, b_out);
}